// Round 20
// baseline (113.181 us; speedup 1.0000x reference)
//
#include <hip/hip_runtime.h>
#include <math.h>

#define Bn 2
#define Sn 2048
#define Dn 1024
#define Hn 16
#define DKn 64
#define Mn (Bn*Sn)

typedef __bf16 bf16;
typedef __attribute__((ext_vector_type(8))) __bf16 bf16x8;
typedef __attribute__((ext_vector_type(4))) __bf16 bf16x4;
typedef __attribute__((ext_vector_type(4))) float f32x4;

__device__ inline f32x4 mfma16(bf16x8 a, bf16x8 b, f32x4 c) {
    return __builtin_amdgcn_mfma_f32_16x16x32_bf16(a, b, c, 0, 0, 0);
}

typedef __attribute__((address_space(3))) void lds_t;
typedef const __attribute__((address_space(1))) void gbl_t;
__device__ __forceinline__ void glds16(const void* g, void* l) {
    __builtin_amdgcn_global_load_lds((gbl_t*)g, (lds_t*)l, 16, 0, 0);
}

// ---------- merged prep: conv3 (6144 blks) + conv_w (2048) + mask_scan (2) ----------
__global__ __launch_bounds__(256)
void prep(const float* __restrict__ q_in, const float* __restrict__ k_in,
          const float* __restrict__ v_in, const float* __restrict__ w_q,
          const float* __restrict__ w_k, const float* __restrict__ w_v,
          const float* __restrict__ w_o, const int* __restrict__ mask,
          bf16* __restrict__ Aq, bf16* __restrict__ Ak, bf16* __restrict__ Av,
          bf16* __restrict__ Wq, bf16* __restrict__ Wk, bf16* __restrict__ Wv,
          bf16* __restrict__ Wo, int* __restrict__ inv, int* __restrict__ cnt)
{
    const int bid = blockIdx.x;
    if (bid < 8192) {
        const float* s; bf16* d; int i;
        if (bid < 6144) {
            int y = bid / 2048, x = bid - y * 2048;
            s = y == 0 ? q_in : y == 1 ? k_in : v_in;
            d = y == 0 ? Aq   : y == 1 ? Ak   : Av;
            i = (x * 256 + threadIdx.x) * 8;
        } else {
            int r = bid - 6144;
            int y = r / 512, x = r - y * 512;
            s = y == 0 ? w_q : y == 1 ? w_k : y == 2 ? w_v : w_o;
            d = y == 0 ? Wq  : y == 1 ? Wk  : y == 2 ? Wv  : Wo;
            i = (x * 256 + threadIdx.x) * 8;
        }
        float4 a = *(const float4*)(s + i);
        float4 b = *(const float4*)(s + i + 4);
        bf16x8 o;
        o[0]=(bf16)a.x; o[1]=(bf16)a.y; o[2]=(bf16)a.z; o[3]=(bf16)a.w;
        o[4]=(bf16)b.x; o[5]=(bf16)b.y; o[6]=(bf16)b.z; o[7]=(bf16)b.w;
        *(bf16x8*)(d + i) = o;
    } else {
        if (threadIdx.x >= 64) return;
        const int b    = bid - 8192;
        const int lane = threadIdx.x;
        const int* mb  = mask + b * Sn;
        int loc[32];
        int c = 0;
        #pragma unroll
        for (int e = 0; e < 32; ++e) {
            loc[e] = (mb[lane * 32 + e] != 0) ? 1 : 0;
            c += loc[e];
        }
        int pre = c;
        #pragma unroll
        for (int off = 1; off < 64; off <<= 1) {
            int v = __shfl_up(pre, off);
            if (lane >= off) pre += v;
        }
        int excl  = pre - c;
        int total = __shfl(pre, 63);
        int un = excl;
        int ms = lane * 32 - excl;
        #pragma unroll
        for (int e = 0; e < 32; ++e) {
            int s = lane * 32 + e;
            if (loc[e]) { inv[b * Sn + un] = s;           ++un; }
            else        { inv[b * Sn + total + ms] = s;   ++ms; }
        }
        if (lane == 63) cnt[b] = total;
    }
}

// ---------- projection GEMM: 128x128, BK=64, swizzled LDS, zero-padded slots ----------
// z==0: Q (all rows) scaled log2(e)/8 -> [B,H,S,DK].
// z==1: K — slots [s0,s0+128), rows via inv -> [B,H,slot,DK]; slots >= cnt -> 0.
// z==2: V — same gather -> [B,H,DK,slot]; slots >= cnt -> 0.
// Zero-padding lets attention treat every tile uniformly (pad keys contribute
// exp2(0)=1 to the denominator, corrected by one scalar subtract).
__global__ __launch_bounds__(256)
void gemm_proj(const bf16* __restrict__ Aq, const bf16* __restrict__ Ak,
               const bf16* __restrict__ Av, const bf16* __restrict__ Wq,
               const bf16* __restrict__ Wk, const bf16* __restrict__ Wv,
               const float* __restrict__ bq, const float* __restrict__ bk,
               const float* __restrict__ bv, const int* __restrict__ inv,
               const int* __restrict__ cnt,
               bf16* __restrict__ Cq, bf16* __restrict__ Ck, bf16* __restrict__ Cv)
{
    __shared__ bf16 As[128][64];
    __shared__ bf16 Ws_[128][64];

    const int bid = blockIdx.x;
    const int l   = (bid & 7) * 96 + (bid >> 3);   // bijective (768 % 8 == 0)
    const int z   = l >> 8;
    const int rem = l & 255;
    const int mt  = rem >> 3;
    const int n0  = (rem & 7) * 128;
    const int m0  = mt * 128;
    const int bb  = mt >> 4;
    const int s0  = (mt & 15) * 128;

    int eff = Sn;
    if (z >= 1) {
        eff = cnt[bb];
        if (eff == 0) eff = Sn;
        if (s0 >= eff) return;
    }

    const bf16*  A    = z == 0 ? Aq : z == 1 ? Ak : Av;
    const bf16*  W    = z == 0 ? Wq : z == 1 ? Wk : Wv;
    const float* bias = z == 0 ? bq : z == 1 ? bk : bv;
    bf16*        C    = z == 0 ? Cq : z == 1 ? Ck : Cv;

    const int tid = threadIdx.x;
    const int w4 = tid >> 6, ln = tid & 63;
    const int p = ln & 15, g = ln >> 4;
    const int wr = w4 >> 1, wc = w4 & 1;

    const int lr   = ln >> 3;
    const int scol = 8 * ((ln & 7) ^ lr);
    const int sw   = p & 7;

    const bf16* ga[4];
    const bf16* gw[4];
    #pragma unroll
    for (int i = 0; i < 4; ++i) {
        int lrow = w4*32 + i*8 + lr;
        int row;
        if (z == 0) row = m0 + lrow;
        else        row = bb * Sn + inv[bb * Sn + s0 + lrow];
        ga[i] = A + (size_t)row * Dn + scol;
        gw[i] = W + (size_t)(n0 + lrow) * Dn + scol;
    }

    f32x4 acc[4][4];
    #pragma unroll
    for (int mi = 0; mi < 4; ++mi)
        #pragma unroll
        for (int ni = 0; ni < 4; ++ni) acc[mi][ni] = (f32x4){0.f,0.f,0.f,0.f};

    for (int k0 = 0; k0 < Dn; k0 += 64) {
        __syncthreads();
        #pragma unroll
        for (int i = 0; i < 4; ++i) {
            glds16(ga[i] + k0, &As [w4*32 + i*8][0]);
            glds16(gw[i] + k0, &Ws_[w4*32 + i*8][0]);
        }
        __syncthreads();

        #pragma unroll
        for (int kk = 0; kk < 2; ++kk) {
            bf16x8 af[4], bfr[4];
            #pragma unroll
            for (int mi = 0; mi < 4; ++mi)
                af[mi] = *(const bf16x8*)
                    &As[wr*64 + mi*16 + p][8 * ((g + 4*kk) ^ sw)];
            #pragma unroll
            for (int ni = 0; ni < 4; ++ni)
                bfr[ni] = *(const bf16x8*)
                    &Ws_[wc*64 + ni*16 + p][8 * ((g + 4*kk) ^ sw)];
            #pragma unroll
            for (int mi = 0; mi < 4; ++mi)
                #pragma unroll
                for (int ni = 0; ni < 4; ++ni)
                    acc[mi][ni] = mfma16(af[mi], bfr[ni], acc[mi][ni]);
        }
    }

    if (z == 0) {
        const float osc = 0.18033688011112042f;   // log2(e)/8
        #pragma unroll
        for (int ni = 0; ni < 4; ++ni) {
            int n = n0 + wc*64 + ni*16 + p;
            int h = n >> 6, dk = n & (DKn - 1);
            float bv = bias[n];
            #pragma unroll
            for (int mi = 0; mi < 4; ++mi)
                #pragma unroll
                for (int r = 0; r < 4; ++r) {
                    int m = m0 + wr*64 + mi*16 + 4*g + r;
                    int b = m >> 11, s = m & (Sn - 1);
                    C[(((size_t)(b*Hn + h)*Sn + s)*DKn) + dk] =
                        (bf16)((acc[mi][ni][r] + bv) * osc);
                }
        }
    } else if (z == 1) {
        #pragma unroll
        for (int ni = 0; ni < 4; ++ni) {
            int n = n0 + wc*64 + ni*16 + p;
            int h = n >> 6, dk = n & (DKn - 1);
            float bv = bias[n];
            #pragma unroll
            for (int mi = 0; mi < 4; ++mi)
                #pragma unroll
                for (int r = 0; r < 4; ++r) {
                    int jj = s0 + wr*64 + mi*16 + 4*g + r;
                    C[(((size_t)(bb*Hn + h)*Sn + jj)*DKn) + dk] =
                        (bf16)(jj < eff ? acc[mi][ni][r] + bv : 0.f);
                }
        }
    } else {
        #pragma unroll
        for (int ni = 0; ni < 4; ++ni) {
            int n = n0 + wc*64 + ni*16 + p;
            int h = n >> 6, dk = n & (DKn - 1);
            float bv = bias[n];
            #pragma unroll
            for (int mi = 0; mi < 4; ++mi)
                #pragma unroll
                for (int r = 0; r < 4; ++r) {
                    int jj = s0 + wr*64 + mi*16 + 4*g + r;
                    C[(((size_t)(bb*Hn + h)*DKn + dk)*Sn) + jj] =
                        (bf16)(jj < eff ? acc[mi][ni][r] + bv : 0.f);
                }
        }
    }
}

// ---------- output GEMM: 128x64, BK=64, single-buffer, swizzled LDS ----------
__global__ __launch_bounds__(256)
void gemm_out(const bf16* __restrict__ A, const bf16* __restrict__ W,
              const float* __restrict__ bias, float* __restrict__ C)
{
    __shared__ bf16 As[128][64];
    __shared__ bf16 Ws_[64][64];

    const int bid = blockIdx.x;
    const int l   = (bid & 7) * 64 + (bid >> 3);
    const int m0  = (l >> 4) * 128;
    const int n0  = (l & 15) * 64;

    const int tid = threadIdx.x;
    const int w4 = tid >> 6, ln = tid & 63;
    const int p = ln & 15, g = ln >> 4;
    const int wr = w4 >> 1, wc = w4 & 1;

    const int lr   = ln >> 3;
    const int scol = 8 * ((ln & 7) ^ lr);
    const int sw   = p & 7;

    const bf16* ga[4];
    const bf16* gw[2];
    #pragma unroll
    for (int i = 0; i < 4; ++i)
        ga[i] = A + (size_t)(m0 + w4*32 + i*8 + lr) * Dn + scol;
    #pragma unroll
    for (int i = 0; i < 2; ++i)
        gw[i] = W + (size_t)(n0 + w4*16 + i*8 + lr) * Dn + scol;

    f32x4 acc[4][2];
    #pragma unroll
    for (int mi = 0; mi < 4; ++mi)
        #pragma unroll
        for (int ni = 0; ni < 2; ++ni) acc[mi][ni] = (f32x4){0.f,0.f,0.f,0.f};

    for (int k0 = 0; k0 < Dn; k0 += 64) {
        __syncthreads();
        #pragma unroll
        for (int i = 0; i < 4; ++i)
            glds16(ga[i] + k0, &As[w4*32 + i*8][0]);
        #pragma unroll
        for (int i = 0; i < 2; ++i)
            glds16(gw[i] + k0, &Ws_[w4*16 + i*8][0]);
        __syncthreads();

        #pragma unroll
        for (int kk = 0; kk < 2; ++kk) {
            bf16x8 af[4], bfr[2];
            #pragma unroll
            for (int mi = 0; mi < 4; ++mi)
                af[mi] = *(const bf16x8*)
                    &As[wr*64 + mi*16 + p][8 * ((g + 4*kk) ^ sw)];
            #pragma unroll
            for (int ni = 0; ni < 2; ++ni)
                bfr[ni] = *(const bf16x8*)
                    &Ws_[wc*32 + ni*16 + p][8 * ((g + 4*kk) ^ sw)];
            #pragma unroll
            for (int mi = 0; mi < 4; ++mi)
                #pragma unroll
                for (int ni = 0; ni < 2; ++ni)
                    acc[mi][ni] = mfma16(af[mi], bfr[ni], acc[mi][ni]);
        }
    }

    #pragma unroll
    for (int ni = 0; ni < 2; ++ni) {
        int n = n0 + wc*32 + ni*16 + p;
        float bv = bias[n];
        #pragma unroll
        for (int mi = 0; mi < 4; ++mi)
            #pragma unroll
            for (int r = 0; r < 4; ++r) {
                int m = m0 + wr*64 + mi*16 + 4*g + r;
                C[(size_t)m * Dn + n] = acc[mi][ni][r] + bv;
            }
    }
}

// ---------- MFMA flash attention: compacted + zero-padded keys ----------
// All tiles uniform (pad keys have K=V=0 -> p=exp2(0)=1, PV adds 0);
// denominator corrected once: lq -= (nt*64 - cnt).
__global__ __launch_bounds__(512)
void attn_mfma(const bf16* __restrict__ Q, const bf16* __restrict__ K,
               const bf16* __restrict__ Vt, const int* __restrict__ cnt,
               bf16* __restrict__ ctx)
{
    __shared__ bf16 Ks[2][64][64];
    __shared__ bf16 Vs[2][64][64];
    __shared__ bf16 Ps[8][16][72];

    const int tid  = threadIdx.x;
    const int lane = tid & 63;
    const int w    = tid >> 6;
    const int g    = lane >> 4;
    const int p    = lane & 15;
    const int bh   = blockIdx.y;
    const int b    = bh >> 4;
    const int h    = bh & 15;
    const int q0   = blockIdx.x * 128;

    const int  cntb = cnt[b];
    const bool unif = (cntb == 0);
    const int  nt   = unif ? (Sn / 64) : ((cntb + 63) >> 6);

    const bf16* Qb = Q  + (size_t)bh * Sn * DKn;
    const bf16* Kb = K  + (size_t)bh * Sn * DKn;
    const bf16* Vb = Vt + (size_t)bh * DKn * Sn;

    const int sr   = lane >> 3;
    const int scol = 8 * ((lane & 7) ^ sr);
    const int drow = w * 8 + sr;
    const int swzk = (p & 7) << 3;
    const bf16* gK = Kb + (size_t)drow * DKn + scol;
    const bf16* gV = Vb + (size_t)drow * Sn  + scol;

    bf16x8 aq0, aq1;
    {
        const bf16* qrow = Qb + (size_t)(q0 + w*16 + p) * DKn + 8*g;
        aq0 = *(const bf16x8*)(qrow);
        aq1 = *(const bf16x8*)(qrow + 32);
    }

    f32x4 o[4];
    #pragma unroll
    for (int dt = 0; dt < 4; ++dt) o[dt] = (f32x4){0.f,0.f,0.f,0.f};
    float lq = 0.f;

    glds16(gK, &Ks[0][w*8][0]);
    glds16(gV, &Vs[0][w*8][0]);
    __syncthreads();

    int bf = 0;
    for (int kt = 0; kt < nt; ++kt) {
        if (kt + 1 < nt) {
            glds16(gK + (size_t)(kt+1)*64*DKn, &Ks[bf^1][w*8][0]);
            glds16(gV + (size_t)(kt+1)*64,     &Vs[bf^1][w*8][0]);
        }

        #pragma unroll
        for (int t = 0; t < 4; ++t) {
            f32x4 z = (f32x4){0.f,0.f,0.f,0.f};
            bf16x8 k0 = *(const bf16x8*)&Ks[bf][16*t + p][(8*g)      ^ swzk];
            bf16x8 k1 = *(const bf16x8*)&Ks[bf][16*t + p][(8*g + 32) ^ swzk];
            z = mfma16(k0, aq0, z);
            z = mfma16(k1, aq1, z);
            bf16x4 pk;
            if (unif) {
                pk[0] = (bf16)1.f; pk[1] = (bf16)1.f;
                pk[2] = (bf16)1.f; pk[3] = (bf16)1.f;
                lq += 4.f;
            } else {
                pk[0] = (bf16)exp2f(z[0]);
                pk[1] = (bf16)exp2f(z[1]);
                pk[2] = (bf16)exp2f(z[2]);
                pk[3] = (bf16)exp2f(z[3]);
                lq += (float)pk[0] + (float)pk[1] + (float)pk[2] + (float)pk[3];
            }
            *(bf16x4*)&Ps[w][p][16*t + 4*g] = pk;
        }

        bf16x8 pa0 = *(const bf16x8*)&Ps[w][p][8*g];
        bf16x8 pa1 = *(const bf16x8*)&Ps[w][p][32 + 8*g];
        #pragma unroll
        for (int dt = 0; dt < 4; ++dt) {
            bf16x8 v0 = *(const bf16x8*)&Vs[bf][16*dt + p][(8*g)      ^ swzk];
            bf16x8 v1 = *(const bf16x8*)&Vs[bf][16*dt + p][(8*g + 32) ^ swzk];
            o[dt] = mfma16(pa0, v0, o[dt]);
            o[dt] = mfma16(pa1, v1, o[dt]);
        }

        __syncthreads();
        bf ^= 1;
    }

    lq += __shfl_xor(lq, 16);
    lq += __shfl_xor(lq, 32);
    if (!unif) lq -= (float)(nt * 64 - cntb);   // remove pad keys' exp2(0)=1
    float ld[4];
    #pragma unroll
    for (int r = 0; r < 4; ++r) ld[r] = __shfl(lq, 4*g + r);

    #pragma unroll
    for (int dt = 0; dt < 4; ++dt)
        #pragma unroll
        for (int r = 0; r < 4; ++r) {
            int s_ = q0 + w*16 + 4*g + r;
            ctx[(size_t)(b*Sn + s_) * Dn + h*64 + 16*dt + p] =
                (bf16)(o[dt][r] / ld[r]);
        }
}

extern "C" void kernel_launch(void* const* d_in, const int* in_sizes, int n_in,
                              void* d_out, int out_size, void* d_ws, size_t ws_size,
                              hipStream_t stream) {
    const float* q_in = (const float*)d_in[0];
    const float* k_in = (const float*)d_in[1];
    const float* v_in = (const float*)d_in[2];
    const int*   mask = (const int*)  d_in[3];
    const float* w_q  = (const float*)d_in[4];
    const float* b_q  = (const float*)d_in[5];
    const float* w_k  = (const float*)d_in[6];
    const float* b_k  = (const float*)d_in[7];
    const float* w_v  = (const float*)d_in[8];
    const float* b_v  = (const float*)d_in[9];
    const float* w_o  = (const float*)d_in[10];
    const float* b_o  = (const float*)d_in[11];

    char* ws = (char*)d_ws;
    bf16* Abf_q = (bf16*)(ws);
    bf16* Abf_k = (bf16*)(ws + 8388608);
    bf16* Abf_v = (bf16*)(ws + 16777216);
    bf16* ctx   = (bf16*)(ws);                // aliases Abf_q after proj consumes it
    bf16* Qh    = (bf16*)(ws + 25165824);
    bf16* Kh    = (bf16*)(ws + 33554432);
    bf16* Vt    = (bf16*)(ws + 41943040);
    bf16* Wbf_q = (bf16*)(ws + 50331648);
    bf16* Wbf_k = (bf16*)(ws + 52428800);
    bf16* Wbf_v = (bf16*)(ws + 54525952);
    bf16* Wbf_o = (bf16*)(ws + 56623104);
    int*  inv   = (int*) (ws + 58720256);
    int*  cntb  = (int*) (ws + 58736640);

    dim3 blk(256);
    prep<<<dim3(8194), blk, 0, stream>>>(q_in, k_in, v_in, w_q, w_k, w_v, w_o,
                                         mask, Abf_q, Abf_k, Abf_v,
                                         Wbf_q, Wbf_k, Wbf_v, Wbf_o, inv, cntb);

    gemm_proj<<<dim3(768), blk, 0, stream>>>(
        Abf_q, Abf_k, Abf_v, Wbf_q, Wbf_k, Wbf_v, b_q, b_k, b_v, inv, cntb,
        Qh, Kh, Vt);

    attn_mfma<<<dim3(Sn/128, Bn*Hn), dim3(512), 0, stream>>>(Qh, Kh, Vt, cntb, ctx);

    gemm_out<<<dim3(512), blk, 0, stream>>>(ctx, Wbf_o, b_o, (float*)d_out);
}

// Round 21
// 107.907 us; speedup vs baseline: 1.0489x; 1.0489x over previous
//
#include <hip/hip_runtime.h>
#include <math.h>

#define Bn 2
#define Sn 2048
#define Dn 1024
#define Hn 16
#define DKn 64
#define Mn (Bn*Sn)

typedef __bf16 bf16;
typedef __attribute__((ext_vector_type(8))) __bf16 bf16x8;
typedef __attribute__((ext_vector_type(4))) __bf16 bf16x4;
typedef __attribute__((ext_vector_type(4))) float f32x4;

__device__ inline f32x4 mfma16(bf16x8 a, bf16x8 b, f32x4 c) {
    return __builtin_amdgcn_mfma_f32_16x16x32_bf16(a, b, c, 0, 0, 0);
}

typedef __attribute__((address_space(3))) void lds_t;
typedef const __attribute__((address_space(1))) void gbl_t;
__device__ __forceinline__ void glds16(const void* g, void* l) {
    __builtin_amdgcn_global_load_lds((gbl_t*)g, (lds_t*)l, 16, 0, 0);
}

// ---------- merged prep: conv3 (6144 blks) + conv_w (2048) + mask_scan (2) ----------
__global__ __launch_bounds__(256)
void prep(const float* __restrict__ q_in, const float* __restrict__ k_in,
          const float* __restrict__ v_in, const float* __restrict__ w_q,
          const float* __restrict__ w_k, const float* __restrict__ w_v,
          const float* __restrict__ w_o, const int* __restrict__ mask,
          bf16* __restrict__ Aq, bf16* __restrict__ Ak, bf16* __restrict__ Av,
          bf16* __restrict__ Wq, bf16* __restrict__ Wk, bf16* __restrict__ Wv,
          bf16* __restrict__ Wo, int* __restrict__ inv, int* __restrict__ cnt)
{
    const int bid = blockIdx.x;
    if (bid < 8192) {
        const float* s; bf16* d; int i;
        if (bid < 6144) {
            int y = bid / 2048, x = bid - y * 2048;
            s = y == 0 ? q_in : y == 1 ? k_in : v_in;
            d = y == 0 ? Aq   : y == 1 ? Ak   : Av;
            i = (x * 256 + threadIdx.x) * 8;
        } else {
            int r = bid - 6144;
            int y = r / 512, x = r - y * 512;
            s = y == 0 ? w_q : y == 1 ? w_k : y == 2 ? w_v : w_o;
            d = y == 0 ? Wq  : y == 1 ? Wk  : y == 2 ? Wv  : Wo;
            i = (x * 256 + threadIdx.x) * 8;
        }
        float4 a = *(const float4*)(s + i);
        float4 b = *(const float4*)(s + i + 4);
        bf16x8 o;
        o[0]=(bf16)a.x; o[1]=(bf16)a.y; o[2]=(bf16)a.z; o[3]=(bf16)a.w;
        o[4]=(bf16)b.x; o[5]=(bf16)b.y; o[6]=(bf16)b.z; o[7]=(bf16)b.w;
        *(bf16x8*)(d + i) = o;
    } else {
        if (threadIdx.x >= 64) return;
        const int b    = bid - 8192;
        const int lane = threadIdx.x;
        const int* mb  = mask + b * Sn;
        int loc[32];
        int c = 0;
        #pragma unroll
        for (int e = 0; e < 32; ++e) {
            loc[e] = (mb[lane * 32 + e] != 0) ? 1 : 0;
            c += loc[e];
        }
        int pre = c;
        #pragma unroll
        for (int off = 1; off < 64; off <<= 1) {
            int v = __shfl_up(pre, off);
            if (lane >= off) pre += v;
        }
        int excl  = pre - c;
        int total = __shfl(pre, 63);
        int un = excl;
        int ms = lane * 32 - excl;
        #pragma unroll
        for (int e = 0; e < 32; ++e) {
            int s = lane * 32 + e;
            if (loc[e]) { inv[b * Sn + un] = s;           ++un; }
            else        { inv[b * Sn + total + ms] = s;   ++ms; }
        }
        if (lane == 63) cnt[b] = total;
    }
}

// ---------- projection GEMM: 128x128, BK=64, swizzled LDS, zero-padded slots ----------
__global__ __launch_bounds__(256)
void gemm_proj(const bf16* __restrict__ Aq, const bf16* __restrict__ Ak,
               const bf16* __restrict__ Av, const bf16* __restrict__ Wq,
               const bf16* __restrict__ Wk, const bf16* __restrict__ Wv,
               const float* __restrict__ bq, const float* __restrict__ bk,
               const float* __restrict__ bv, const int* __restrict__ inv,
               const int* __restrict__ cnt,
               bf16* __restrict__ Cq, bf16* __restrict__ Ck, bf16* __restrict__ Cv)
{
    __shared__ bf16 As[128][64];
    __shared__ bf16 Ws_[128][64];

    const int bid = blockIdx.x;
    const int l   = (bid & 7) * 96 + (bid >> 3);   // bijective (768 % 8 == 0)
    const int z   = l >> 8;
    const int rem = l & 255;
    const int mt  = rem >> 3;
    const int n0  = (rem & 7) * 128;
    const int m0  = mt * 128;
    const int bb  = mt >> 4;
    const int s0  = (mt & 15) * 128;

    int eff = Sn;
    if (z >= 1) {
        eff = cnt[bb];
        if (eff == 0) eff = Sn;
        if (s0 >= eff) return;
    }

    const bf16*  A    = z == 0 ? Aq : z == 1 ? Ak : Av;
    const bf16*  W    = z == 0 ? Wq : z == 1 ? Wk : Wv;
    const float* bias = z == 0 ? bq : z == 1 ? bk : bv;
    bf16*        C    = z == 0 ? Cq : z == 1 ? Ck : Cv;

    const int tid = threadIdx.x;
    const int w4 = tid >> 6, ln = tid & 63;
    const int p = ln & 15, g = ln >> 4;
    const int wr = w4 >> 1, wc = w4 & 1;

    const int lr   = ln >> 3;
    const int scol = 8 * ((ln & 7) ^ lr);
    const int sw   = p & 7;

    const bf16* ga[4];
    const bf16* gw[4];
    #pragma unroll
    for (int i = 0; i < 4; ++i) {
        int lrow = w4*32 + i*8 + lr;
        int row;
        if (z == 0) row = m0 + lrow;
        else        row = bb * Sn + inv[bb * Sn + s0 + lrow];
        ga[i] = A + (size_t)row * Dn + scol;
        gw[i] = W + (size_t)(n0 + lrow) * Dn + scol;
    }

    f32x4 acc[4][4];
    #pragma unroll
    for (int mi = 0; mi < 4; ++mi)
        #pragma unroll
        for (int ni = 0; ni < 4; ++ni) acc[mi][ni] = (f32x4){0.f,0.f,0.f,0.f};

    for (int k0 = 0; k0 < Dn; k0 += 64) {
        __syncthreads();
        #pragma unroll
        for (int i = 0; i < 4; ++i) {
            glds16(ga[i] + k0, &As [w4*32 + i*8][0]);
            glds16(gw[i] + k0, &Ws_[w4*32 + i*8][0]);
        }
        __syncthreads();

        #pragma unroll
        for (int kk = 0; kk < 2; ++kk) {
            bf16x8 af[4], bfr[4];
            #pragma unroll
            for (int mi = 0; mi < 4; ++mi)
                af[mi] = *(const bf16x8*)
                    &As[wr*64 + mi*16 + p][8 * ((g + 4*kk) ^ sw)];
            #pragma unroll
            for (int ni = 0; ni < 4; ++ni)
                bfr[ni] = *(const bf16x8*)
                    &Ws_[wc*64 + ni*16 + p][8 * ((g + 4*kk) ^ sw)];
            #pragma unroll
            for (int mi = 0; mi < 4; ++mi)
                #pragma unroll
                for (int ni = 0; ni < 4; ++ni)
                    acc[mi][ni] = mfma16(af[mi], bfr[ni], acc[mi][ni]);
        }
    }

    if (z == 0) {
        const float osc = 0.18033688011112042f;   // log2(e)/8
        #pragma unroll
        for (int ni = 0; ni < 4; ++ni) {
            int n = n0 + wc*64 + ni*16 + p;
            int h = n >> 6, dk = n & (DKn - 1);
            float bv = bias[n];
            #pragma unroll
            for (int mi = 0; mi < 4; ++mi)
                #pragma unroll
                for (int r = 0; r < 4; ++r) {
                    int m = m0 + wr*64 + mi*16 + 4*g + r;
                    int b = m >> 11, s = m & (Sn - 1);
                    C[(((size_t)(b*Hn + h)*Sn + s)*DKn) + dk] =
                        (bf16)((acc[mi][ni][r] + bv) * osc);
                }
        }
    } else if (z == 1) {
        #pragma unroll
        for (int ni = 0; ni < 4; ++ni) {
            int n = n0 + wc*64 + ni*16 + p;
            int h = n >> 6, dk = n & (DKn - 1);
            float bv = bias[n];
            #pragma unroll
            for (int mi = 0; mi < 4; ++mi)
                #pragma unroll
                for (int r = 0; r < 4; ++r) {
                    int jj = s0 + wr*64 + mi*16 + 4*g + r;
                    C[(((size_t)(bb*Hn + h)*Sn + jj)*DKn) + dk] =
                        (bf16)(jj < eff ? acc[mi][ni][r] + bv : 0.f);
                }
        }
    } else {
        #pragma unroll
        for (int ni = 0; ni < 4; ++ni) {
            int n = n0 + wc*64 + ni*16 + p;
            int h = n >> 6, dk = n & (DKn - 1);
            float bv = bias[n];
            #pragma unroll
            for (int mi = 0; mi < 4; ++mi)
                #pragma unroll
                for (int r = 0; r < 4; ++r) {
                    int jj = s0 + wr*64 + mi*16 + 4*g + r;
                    C[(((size_t)(bb*Hn + h)*DKn + dk)*Sn) + jj] =
                        (bf16)(jj < eff ? acc[mi][ni][r] + bv : 0.f);
                }
        }
    }
}

// ---------- output GEMM: 128x64, BK=64, single-buffer, swizzled LDS ----------
__global__ __launch_bounds__(256)
void gemm_out(const bf16* __restrict__ A, const bf16* __restrict__ W,
              const float* __restrict__ bias, float* __restrict__ C)
{
    __shared__ bf16 As[128][64];
    __shared__ bf16 Ws_[64][64];

    const int bid = blockIdx.x;
    const int l   = (bid & 7) * 64 + (bid >> 3);
    const int m0  = (l >> 4) * 128;
    const int n0  = (l & 15) * 64;

    const int tid = threadIdx.x;
    const int w4 = tid >> 6, ln = tid & 63;
    const int p = ln & 15, g = ln >> 4;
    const int wr = w4 >> 1, wc = w4 & 1;

    const int lr   = ln >> 3;
    const int scol = 8 * ((ln & 7) ^ lr);
    const int sw   = p & 7;

    const bf16* ga[4];
    const bf16* gw[2];
    #pragma unroll
    for (int i = 0; i < 4; ++i)
        ga[i] = A + (size_t)(m0 + w4*32 + i*8 + lr) * Dn + scol;
    #pragma unroll
    for (int i = 0; i < 2; ++i)
        gw[i] = W + (size_t)(n0 + w4*16 + i*8 + lr) * Dn + scol;

    f32x4 acc[4][2];
    #pragma unroll
    for (int mi = 0; mi < 4; ++mi)
        #pragma unroll
        for (int ni = 0; ni < 2; ++ni) acc[mi][ni] = (f32x4){0.f,0.f,0.f,0.f};

    for (int k0 = 0; k0 < Dn; k0 += 64) {
        __syncthreads();
        #pragma unroll
        for (int i = 0; i < 4; ++i)
            glds16(ga[i] + k0, &As[w4*32 + i*8][0]);
        #pragma unroll
        for (int i = 0; i < 2; ++i)
            glds16(gw[i] + k0, &Ws_[w4*16 + i*8][0]);
        __syncthreads();

        #pragma unroll
        for (int kk = 0; kk < 2; ++kk) {
            bf16x8 af[4], bfr[2];
            #pragma unroll
            for (int mi = 0; mi < 4; ++mi)
                af[mi] = *(const bf16x8*)
                    &As[wr*64 + mi*16 + p][8 * ((g + 4*kk) ^ sw)];
            #pragma unroll
            for (int ni = 0; ni < 2; ++ni)
                bfr[ni] = *(const bf16x8*)
                    &Ws_[wc*32 + ni*16 + p][8 * ((g + 4*kk) ^ sw)];
            #pragma unroll
            for (int mi = 0; mi < 4; ++mi)
                #pragma unroll
                for (int ni = 0; ni < 2; ++ni)
                    acc[mi][ni] = mfma16(af[mi], bfr[ni], acc[mi][ni]);
        }
    }

    #pragma unroll
    for (int ni = 0; ni < 2; ++ni) {
        int n = n0 + wc*32 + ni*16 + p;
        float bv = bias[n];
        #pragma unroll
        for (int mi = 0; mi < 4; ++mi)
            #pragma unroll
            for (int r = 0; r < 4; ++r) {
                int m = m0 + wr*64 + mi*16 + 4*g + r;
                C[(size_t)m * Dn + n] = acc[mi][ni][r] + bv;
            }
    }
}

// ---------- MFMA flash attention: compacted + zero-padded keys ----------
// Denominator accumulated from f32 exps (tree) — drops 16 cvt-backs/iter;
// RNE rounding noise vs rounded-P denominator ~1e-5 relative (negligible).
__global__ __launch_bounds__(512)
void attn_mfma(const bf16* __restrict__ Q, const bf16* __restrict__ K,
               const bf16* __restrict__ Vt, const int* __restrict__ cnt,
               bf16* __restrict__ ctx)
{
    __shared__ bf16 Ks[2][64][64];
    __shared__ bf16 Vs[2][64][64];
    __shared__ bf16 Ps[8][16][72];

    const int tid  = threadIdx.x;
    const int lane = tid & 63;
    const int w    = tid >> 6;
    const int g    = lane >> 4;
    const int p    = lane & 15;
    const int bh   = blockIdx.y;
    const int b    = bh >> 4;
    const int h    = bh & 15;
    const int q0   = blockIdx.x * 128;

    const int  cntb = cnt[b];
    const bool unif = (cntb == 0);
    const int  nt   = unif ? (Sn / 64) : ((cntb + 63) >> 6);

    const bf16* Qb = Q  + (size_t)bh * Sn * DKn;
    const bf16* Kb = K  + (size_t)bh * Sn * DKn;
    const bf16* Vb = Vt + (size_t)bh * DKn * Sn;

    const int sr   = lane >> 3;
    const int scol = 8 * ((lane & 7) ^ sr);
    const int drow = w * 8 + sr;
    const int swzk = (p & 7) << 3;
    const bf16* gK = Kb + (size_t)drow * DKn + scol;
    const bf16* gV = Vb + (size_t)drow * Sn  + scol;

    bf16x8 aq0, aq1;
    {
        const bf16* qrow = Qb + (size_t)(q0 + w*16 + p) * DKn + 8*g;
        aq0 = *(const bf16x8*)(qrow);
        aq1 = *(const bf16x8*)(qrow + 32);
    }

    f32x4 o[4];
    #pragma unroll
    for (int dt = 0; dt < 4; ++dt) o[dt] = (f32x4){0.f,0.f,0.f,0.f};
    float lq = 0.f;

    glds16(gK, &Ks[0][w*8][0]);
    glds16(gV, &Vs[0][w*8][0]);
    __syncthreads();

    int bf = 0;
    for (int kt = 0; kt < nt; ++kt) {
        if (kt + 1 < nt) {
            glds16(gK + (size_t)(kt+1)*64*DKn, &Ks[bf^1][w*8][0]);
            glds16(gV + (size_t)(kt+1)*64,     &Vs[bf^1][w*8][0]);
        }

        #pragma unroll
        for (int t = 0; t < 4; ++t) {
            f32x4 z = (f32x4){0.f,0.f,0.f,0.f};
            bf16x8 k0 = *(const bf16x8*)&Ks[bf][16*t + p][(8*g)      ^ swzk];
            bf16x8 k1 = *(const bf16x8*)&Ks[bf][16*t + p][(8*g + 32) ^ swzk];
            z = mfma16(k0, aq0, z);
            z = mfma16(k1, aq1, z);
            bf16x4 pk;
            if (unif) {
                pk[0] = (bf16)1.f; pk[1] = (bf16)1.f;
                pk[2] = (bf16)1.f; pk[3] = (bf16)1.f;
                lq += 4.f;
            } else {
                float e0 = exp2f(z[0]);
                float e1 = exp2f(z[1]);
                float e2 = exp2f(z[2]);
                float e3 = exp2f(z[3]);
                pk[0] = (bf16)e0; pk[1] = (bf16)e1;
                pk[2] = (bf16)e2; pk[3] = (bf16)e3;
                lq += (e0 + e1) + (e2 + e3);   // f32 tree, no cvt-back
            }
            *(bf16x4*)&Ps[w][p][16*t + 4*g] = pk;
        }

        bf16x8 pa0 = *(const bf16x8*)&Ps[w][p][8*g];
        bf16x8 pa1 = *(const bf16x8*)&Ps[w][p][32 + 8*g];
        #pragma unroll
        for (int dt = 0; dt < 4; ++dt) {
            bf16x8 v0 = *(const bf16x8*)&Vs[bf][16*dt + p][(8*g)      ^ swzk];
            bf16x8 v1 = *(const bf16x8*)&Vs[bf][16*dt + p][(8*g + 32) ^ swzk];
            o[dt] = mfma16(pa0, v0, o[dt]);
            o[dt] = mfma16(pa1, v1, o[dt]);
        }

        __syncthreads();
        bf ^= 1;
    }

    lq += __shfl_xor(lq, 16);
    lq += __shfl_xor(lq, 32);
    if (!unif) lq -= (float)(nt * 64 - cntb);   // remove pad keys' exp2(0)=1
    float ld[4];
    #pragma unroll
    for (int r = 0; r < 4; ++r) ld[r] = __shfl(lq, 4*g + r);

    #pragma unroll
    for (int dt = 0; dt < 4; ++dt)
        #pragma unroll
        for (int r = 0; r < 4; ++r) {
            int s_ = q0 + w*16 + 4*g + r;
            ctx[(size_t)(b*Sn + s_) * Dn + h*64 + 16*dt + p] =
                (bf16)(o[dt][r] / ld[r]);
        }
}

extern "C" void kernel_launch(void* const* d_in, const int* in_sizes, int n_in,
                              void* d_out, int out_size, void* d_ws, size_t ws_size,
                              hipStream_t stream) {
    const float* q_in = (const float*)d_in[0];
    const float* k_in = (const float*)d_in[1];
    const float* v_in = (const float*)d_in[2];
    const int*   mask = (const int*)  d_in[3];
    const float* w_q  = (const float*)d_in[4];
    const float* b_q  = (const float*)d_in[5];
    const float* w_k  = (const float*)d_in[6];
    const float* b_k  = (const float*)d_in[7];
    const float* w_v  = (const float*)d_in[8];
    const float* b_v  = (const float*)d_in[9];
    const float* w_o  = (const float*)d_in[10];
    const float* b_o  = (const float*)d_in[11];

    char* ws = (char*)d_ws;
    bf16* Abf_q = (bf16*)(ws);
    bf16* Abf_k = (bf16*)(ws + 8388608);
    bf16* Abf_v = (bf16*)(ws + 16777216);
    bf16* ctx   = (bf16*)(ws);                // aliases Abf_q after proj consumes it
    bf16* Qh    = (bf16*)(ws + 25165824);
    bf16* Kh    = (bf16*)(ws + 33554432);
    bf16* Vt    = (bf16*)(ws + 41943040);
    bf16* Wbf_q = (bf16*)(ws + 50331648);
    bf16* Wbf_k = (bf16*)(ws + 52428800);
    bf16* Wbf_v = (bf16*)(ws + 54525952);
    bf16* Wbf_o = (bf16*)(ws + 56623104);
    int*  inv   = (int*) (ws + 58720256);
    int*  cntb  = (int*) (ws + 58736640);

    dim3 blk(256);
    prep<<<dim3(8194), blk, 0, stream>>>(q_in, k_in, v_in, w_q, w_k, w_v, w_o,
                                         mask, Abf_q, Abf_k, Abf_v,
                                         Wbf_q, Wbf_k, Wbf_v, Wbf_o, inv, cntb);

    gemm_proj<<<dim3(768), blk, 0, stream>>>(
        Abf_q, Abf_k, Abf_v, Wbf_q, Wbf_k, Wbf_v, b_q, b_k, b_v, inv, cntb,
        Qh, Kh, Vt);

    attn_mfma<<<dim3(Sn/128, Bn*Hn), dim3(512), 0, stream>>>(Qh, Kh, Vt, cntb, ctx);

    gemm_out<<<dim3(512), blk, 0, stream>>>(ctx, Wbf_o, b_o, (float*)d_out);
}

// Round 22
// 106.087 us; speedup vs baseline: 1.0669x; 1.0172x over previous
//
#include <hip/hip_runtime.h>
#include <math.h>

#define Bn 2
#define Sn 2048
#define Dn 1024
#define Hn 16
#define DKn 64
#define Mn (Bn*Sn)

typedef __bf16 bf16;
typedef __attribute__((ext_vector_type(8))) __bf16 bf16x8;
typedef __attribute__((ext_vector_type(4))) __bf16 bf16x4;
typedef __attribute__((ext_vector_type(4))) float f32x4;

__device__ inline f32x4 mfma16(bf16x8 a, bf16x8 b, f32x4 c) {
    return __builtin_amdgcn_mfma_f32_16x16x32_bf16(a, b, c, 0, 0, 0);
}

typedef __attribute__((address_space(3))) void lds_t;
typedef const __attribute__((address_space(1))) void gbl_t;
__device__ __forceinline__ void glds16(const void* g, void* l) {
    __builtin_amdgcn_global_load_lds((gbl_t*)g, (lds_t*)l, 16, 0, 0);
}

// ---------- merged prep: conv3 (6144 blks) + conv_w (2048) + mask_scan (2) ----------
__global__ __launch_bounds__(256)
void prep(const float* __restrict__ q_in, const float* __restrict__ k_in,
          const float* __restrict__ v_in, const float* __restrict__ w_q,
          const float* __restrict__ w_k, const float* __restrict__ w_v,
          const float* __restrict__ w_o, const int* __restrict__ mask,
          bf16* __restrict__ Aq, bf16* __restrict__ Ak, bf16* __restrict__ Av,
          bf16* __restrict__ Wq, bf16* __restrict__ Wk, bf16* __restrict__ Wv,
          bf16* __restrict__ Wo, int* __restrict__ inv, int* __restrict__ cnt)
{
    const int bid = blockIdx.x;
    if (bid < 8192) {
        const float* s; bf16* d; int i;
        if (bid < 6144) {
            int y = bid / 2048, x = bid - y * 2048;
            s = y == 0 ? q_in : y == 1 ? k_in : v_in;
            d = y == 0 ? Aq   : y == 1 ? Ak   : Av;
            i = (x * 256 + threadIdx.x) * 8;
        } else {
            int r = bid - 6144;
            int y = r / 512, x = r - y * 512;
            s = y == 0 ? w_q : y == 1 ? w_k : y == 2 ? w_v : w_o;
            d = y == 0 ? Wq  : y == 1 ? Wk  : y == 2 ? Wv  : Wo;
            i = (x * 256 + threadIdx.x) * 8;
        }
        float4 a = *(const float4*)(s + i);
        float4 b = *(const float4*)(s + i + 4);
        bf16x8 o;
        o[0]=(bf16)a.x; o[1]=(bf16)a.y; o[2]=(bf16)a.z; o[3]=(bf16)a.w;
        o[4]=(bf16)b.x; o[5]=(bf16)b.y; o[6]=(bf16)b.z; o[7]=(bf16)b.w;
        *(bf16x8*)(d + i) = o;
    } else {
        if (threadIdx.x >= 64) return;
        const int b    = bid - 8192;
        const int lane = threadIdx.x;
        const int* mb  = mask + b * Sn;
        int loc[32];
        int c = 0;
        #pragma unroll
        for (int e = 0; e < 32; ++e) {
            loc[e] = (mb[lane * 32 + e] != 0) ? 1 : 0;
            c += loc[e];
        }
        int pre = c;
        #pragma unroll
        for (int off = 1; off < 64; off <<= 1) {
            int v = __shfl_up(pre, off);
            if (lane >= off) pre += v;
        }
        int excl  = pre - c;
        int total = __shfl(pre, 63);
        int un = excl;
        int ms = lane * 32 - excl;
        #pragma unroll
        for (int e = 0; e < 32; ++e) {
            int s = lane * 32 + e;
            if (loc[e]) { inv[b * Sn + un] = s;           ++un; }
            else        { inv[b * Sn + total + ms] = s;   ++ms; }
        }
        if (lane == 63) cnt[b] = total;
    }
}

// ---------- projection GEMM: 128x128, BK=128, swizzled LDS, zero-padded slots ----------
// 8 K-iters (barriers halved vs BK=64). Staging: instr i covers 4 LDS rows
// (1KB); source col pre-swizzled 8*((ln&15)^(row&15)); reads chunk (g+4kk)^p
// -> uniform banks (validated: SQ_LDS_BANK_CONFLICT==0 at BK=64 same scheme).
__global__ __launch_bounds__(256)
void gemm_proj(const bf16* __restrict__ Aq, const bf16* __restrict__ Ak,
               const bf16* __restrict__ Av, const bf16* __restrict__ Wq,
               const bf16* __restrict__ Wk, const bf16* __restrict__ Wv,
               const float* __restrict__ bq, const float* __restrict__ bk,
               const float* __restrict__ bv, const int* __restrict__ inv,
               const int* __restrict__ cnt,
               bf16* __restrict__ Cq, bf16* __restrict__ Ck, bf16* __restrict__ Cv)
{
    __shared__ bf16 As[128][128];
    __shared__ bf16 Ws_[128][128];

    const int bid = blockIdx.x;
    const int l   = (bid & 7) * 96 + (bid >> 3);   // bijective (768 % 8 == 0)
    const int z   = l >> 8;
    const int rem = l & 255;
    const int mt  = rem >> 3;
    const int n0  = (rem & 7) * 128;
    const int m0  = mt * 128;
    const int bb  = mt >> 4;
    const int s0  = (mt & 15) * 128;

    int eff = Sn;
    if (z >= 1) {
        eff = cnt[bb];
        if (eff == 0) eff = Sn;
        if (s0 >= eff) return;
    }

    const bf16*  A    = z == 0 ? Aq : z == 1 ? Ak : Av;
    const bf16*  W    = z == 0 ? Wq : z == 1 ? Wk : Wv;
    const float* bias = z == 0 ? bq : z == 1 ? bk : bv;
    bf16*        C    = z == 0 ? Cq : z == 1 ? Ck : Cv;

    const int tid = threadIdx.x;
    const int w4 = tid >> 6, ln = tid & 63;
    const int p = ln & 15, g = ln >> 4;
    const int wr = w4 >> 1, wc = w4 & 1;

    const int lrw = ln >> 4;           // row-within-instr 0..3
    const int lch = ln & 15;           // chunk 0..15

    const bf16* ga[8];
    const bf16* gw[8];
    #pragma unroll
    for (int i = 0; i < 8; ++i) {
        int lrow = w4*32 + i*4 + lrw;
        int scol = 8 * (lch ^ (lrow & 15));
        int row;
        if (z == 0) row = m0 + lrow;
        else        row = bb * Sn + inv[bb * Sn + s0 + lrow];
        ga[i] = A + (size_t)row * Dn + scol;
        gw[i] = W + (size_t)(n0 + lrow) * Dn + scol;
    }

    f32x4 acc[4][4];
    #pragma unroll
    for (int mi = 0; mi < 4; ++mi)
        #pragma unroll
        for (int ni = 0; ni < 4; ++ni) acc[mi][ni] = (f32x4){0.f,0.f,0.f,0.f};

    for (int k0 = 0; k0 < Dn; k0 += 128) {
        __syncthreads();
        #pragma unroll
        for (int i = 0; i < 8; ++i) {
            glds16(ga[i] + k0, &As [w4*32 + i*4][0]);
            glds16(gw[i] + k0, &Ws_[w4*32 + i*4][0]);
        }
        __syncthreads();

        #pragma unroll
        for (int kk = 0; kk < 4; ++kk) {
            bf16x8 af[4], bfr[4];
            #pragma unroll
            for (int mi = 0; mi < 4; ++mi)
                af[mi] = *(const bf16x8*)
                    &As[wr*64 + mi*16 + p][8 * ((g + 4*kk) ^ p)];
            #pragma unroll
            for (int ni = 0; ni < 4; ++ni)
                bfr[ni] = *(const bf16x8*)
                    &Ws_[wc*64 + ni*16 + p][8 * ((g + 4*kk) ^ p)];
            #pragma unroll
            for (int mi = 0; mi < 4; ++mi)
                #pragma unroll
                for (int ni = 0; ni < 4; ++ni)
                    acc[mi][ni] = mfma16(af[mi], bfr[ni], acc[mi][ni]);
        }
    }

    if (z == 0) {
        const float osc = 0.18033688011112042f;   // log2(e)/8
        #pragma unroll
        for (int ni = 0; ni < 4; ++ni) {
            int n = n0 + wc*64 + ni*16 + p;
            int h = n >> 6, dk = n & (DKn - 1);
            float bv = bias[n];
            #pragma unroll
            for (int mi = 0; mi < 4; ++mi)
                #pragma unroll
                for (int r = 0; r < 4; ++r) {
                    int m = m0 + wr*64 + mi*16 + 4*g + r;
                    int b = m >> 11, s = m & (Sn - 1);
                    C[(((size_t)(b*Hn + h)*Sn + s)*DKn) + dk] =
                        (bf16)((acc[mi][ni][r] + bv) * osc);
                }
        }
    } else if (z == 1) {
        #pragma unroll
        for (int ni = 0; ni < 4; ++ni) {
            int n = n0 + wc*64 + ni*16 + p;
            int h = n >> 6, dk = n & (DKn - 1);
            float bv = bias[n];
            #pragma unroll
            for (int mi = 0; mi < 4; ++mi)
                #pragma unroll
                for (int r = 0; r < 4; ++r) {
                    int jj = s0 + wr*64 + mi*16 + 4*g + r;
                    C[(((size_t)(bb*Hn + h)*Sn + jj)*DKn) + dk] =
                        (bf16)(jj < eff ? acc[mi][ni][r] + bv : 0.f);
                }
        }
    } else {
        #pragma unroll
        for (int ni = 0; ni < 4; ++ni) {
            int n = n0 + wc*64 + ni*16 + p;
            int h = n >> 6, dk = n & (DKn - 1);
            float bv = bias[n];
            #pragma unroll
            for (int mi = 0; mi < 4; ++mi)
                #pragma unroll
                for (int r = 0; r < 4; ++r) {
                    int jj = s0 + wr*64 + mi*16 + 4*g + r;
                    C[(((size_t)(bb*Hn + h)*DKn + dk)*Sn) + jj] =
                        (bf16)(jj < eff ? acc[mi][ni][r] + bv : 0.f);
                }
        }
    }
}

// ---------- output GEMM: 128x64, BK=128, swizzled LDS ----------
__global__ __launch_bounds__(256)
void gemm_out(const bf16* __restrict__ A, const bf16* __restrict__ W,
              const float* __restrict__ bias, float* __restrict__ C)
{
    __shared__ bf16 As[128][128];
    __shared__ bf16 Ws_[64][128];

    const int bid = blockIdx.x;
    const int l   = (bid & 7) * 64 + (bid >> 3);
    const int m0  = (l >> 4) * 128;
    const int n0  = (l & 15) * 64;

    const int tid = threadIdx.x;
    const int w4 = tid >> 6, ln = tid & 63;
    const int p = ln & 15, g = ln >> 4;
    const int wr = w4 >> 1, wc = w4 & 1;

    const int lrw = ln >> 4;
    const int lch = ln & 15;

    const bf16* ga[8];
    const bf16* gw[4];
    #pragma unroll
    for (int i = 0; i < 8; ++i) {
        int lrow = w4*32 + i*4 + lrw;
        ga[i] = A + (size_t)(m0 + lrow) * Dn + 8 * (lch ^ (lrow & 15));
    }
    #pragma unroll
    for (int i = 0; i < 4; ++i) {
        int lrow = w4*16 + i*4 + lrw;
        gw[i] = W + (size_t)(n0 + lrow) * Dn + 8 * (lch ^ (lrow & 15));
    }

    f32x4 acc[4][2];
    #pragma unroll
    for (int mi = 0; mi < 4; ++mi)
        #pragma unroll
        for (int ni = 0; ni < 2; ++ni) acc[mi][ni] = (f32x4){0.f,0.f,0.f,0.f};

    for (int k0 = 0; k0 < Dn; k0 += 128) {
        __syncthreads();
        #pragma unroll
        for (int i = 0; i < 8; ++i)
            glds16(ga[i] + k0, &As[w4*32 + i*4][0]);
        #pragma unroll
        for (int i = 0; i < 4; ++i)
            glds16(gw[i] + k0, &Ws_[w4*16 + i*4][0]);
        __syncthreads();

        #pragma unroll
        for (int kk = 0; kk < 4; ++kk) {
            bf16x8 af[4], bfr[2];
            #pragma unroll
            for (int mi = 0; mi < 4; ++mi)
                af[mi] = *(const bf16x8*)
                    &As[wr*64 + mi*16 + p][8 * ((g + 4*kk) ^ p)];
            #pragma unroll
            for (int ni = 0; ni < 2; ++ni)
                bfr[ni] = *(const bf16x8*)
                    &Ws_[wc*32 + ni*16 + p][8 * ((g + 4*kk) ^ p)];
            #pragma unroll
            for (int mi = 0; mi < 4; ++mi)
                #pragma unroll
                for (int ni = 0; ni < 2; ++ni)
                    acc[mi][ni] = mfma16(af[mi], bfr[ni], acc[mi][ni]);
        }
    }

    #pragma unroll
    for (int ni = 0; ni < 2; ++ni) {
        int n = n0 + wc*32 + ni*16 + p;
        float bv = bias[n];
        #pragma unroll
        for (int mi = 0; mi < 4; ++mi)
            #pragma unroll
            for (int r = 0; r < 4; ++r) {
                int m = m0 + wr*64 + mi*16 + 4*g + r;
                C[(size_t)m * Dn + n] = acc[mi][ni][r] + bv;
            }
    }
}

// ---------- MFMA flash attention: compacted + zero-padded keys (r21 exact) ----------
__global__ __launch_bounds__(512)
void attn_mfma(const bf16* __restrict__ Q, const bf16* __restrict__ K,
               const bf16* __restrict__ Vt, const int* __restrict__ cnt,
               bf16* __restrict__ ctx)
{
    __shared__ bf16 Ks[2][64][64];
    __shared__ bf16 Vs[2][64][64];
    __shared__ bf16 Ps[8][16][72];

    const int tid  = threadIdx.x;
    const int lane = tid & 63;
    const int w    = tid >> 6;
    const int g    = lane >> 4;
    const int p    = lane & 15;
    const int bh   = blockIdx.y;
    const int b    = bh >> 4;
    const int h    = bh & 15;
    const int q0   = blockIdx.x * 128;

    const int  cntb = cnt[b];
    const bool unif = (cntb == 0);
    const int  nt   = unif ? (Sn / 64) : ((cntb + 63) >> 6);

    const bf16* Qb = Q  + (size_t)bh * Sn * DKn;
    const bf16* Kb = K  + (size_t)bh * Sn * DKn;
    const bf16* Vb = Vt + (size_t)bh * DKn * Sn;

    const int sr   = lane >> 3;
    const int scol = 8 * ((lane & 7) ^ sr);
    const int drow = w * 8 + sr;
    const int swzk = (p & 7) << 3;
    const bf16* gK = Kb + (size_t)drow * DKn + scol;
    const bf16* gV = Vb + (size_t)drow * Sn  + scol;

    bf16x8 aq0, aq1;
    {
        const bf16* qrow = Qb + (size_t)(q0 + w*16 + p) * DKn + 8*g;
        aq0 = *(const bf16x8*)(qrow);
        aq1 = *(const bf16x8*)(qrow + 32);
    }

    f32x4 o[4];
    #pragma unroll
    for (int dt = 0; dt < 4; ++dt) o[dt] = (f32x4){0.f,0.f,0.f,0.f};
    float lq = 0.f;

    glds16(gK, &Ks[0][w*8][0]);
    glds16(gV, &Vs[0][w*8][0]);
    __syncthreads();

    int bf = 0;
    for (int kt = 0; kt < nt; ++kt) {
        if (kt + 1 < nt) {
            glds16(gK + (size_t)(kt+1)*64*DKn, &Ks[bf^1][w*8][0]);
            glds16(gV + (size_t)(kt+1)*64,     &Vs[bf^1][w*8][0]);
        }

        #pragma unroll
        for (int t = 0; t < 4; ++t) {
            f32x4 z = (f32x4){0.f,0.f,0.f,0.f};
            bf16x8 k0 = *(const bf16x8*)&Ks[bf][16*t + p][(8*g)      ^ swzk];
            bf16x8 k1 = *(const bf16x8*)&Ks[bf][16*t + p][(8*g + 32) ^ swzk];
            z = mfma16(k0, aq0, z);
            z = mfma16(k1, aq1, z);
            bf16x4 pk;
            if (unif) {
                pk[0] = (bf16)1.f; pk[1] = (bf16)1.f;
                pk[2] = (bf16)1.f; pk[3] = (bf16)1.f;
                lq += 4.f;
            } else {
                float e0 = exp2f(z[0]);
                float e1 = exp2f(z[1]);
                float e2 = exp2f(z[2]);
                float e3 = exp2f(z[3]);
                pk[0] = (bf16)e0; pk[1] = (bf16)e1;
                pk[2] = (bf16)e2; pk[3] = (bf16)e3;
                lq += (e0 + e1) + (e2 + e3);
            }
            *(bf16x4*)&Ps[w][p][16*t + 4*g] = pk;
        }

        bf16x8 pa0 = *(const bf16x8*)&Ps[w][p][8*g];
        bf16x8 pa1 = *(const bf16x8*)&Ps[w][p][32 + 8*g];
        #pragma unroll
        for (int dt = 0; dt < 4; ++dt) {
            bf16x8 v0 = *(const bf16x8*)&Vs[bf][16*dt + p][(8*g)      ^ swzk];
            bf16x8 v1 = *(const bf16x8*)&Vs[bf][16*dt + p][(8*g + 32) ^ swzk];
            o[dt] = mfma16(pa0, v0, o[dt]);
            o[dt] = mfma16(pa1, v1, o[dt]);
        }

        __syncthreads();
        bf ^= 1;
    }

    lq += __shfl_xor(lq, 16);
    lq += __shfl_xor(lq, 32);
    if (!unif) lq -= (float)(nt * 64 - cntb);   // remove pad keys' exp2(0)=1
    float ld[4];
    #pragma unroll
    for (int r = 0; r < 4; ++r) ld[r] = __shfl(lq, 4*g + r);

    #pragma unroll
    for (int dt = 0; dt < 4; ++dt)
        #pragma unroll
        for (int r = 0; r < 4; ++r) {
            int s_ = q0 + w*16 + 4*g + r;
            ctx[(size_t)(b*Sn + s_) * Dn + h*64 + 16*dt + p] =
                (bf16)(o[dt][r] / ld[r]);
        }
}

extern "C" void kernel_launch(void* const* d_in, const int* in_sizes, int n_in,
                              void* d_out, int out_size, void* d_ws, size_t ws_size,
                              hipStream_t stream) {
    const float* q_in = (const float*)d_in[0];
    const float* k_in = (const float*)d_in[1];
    const float* v_in = (const float*)d_in[2];
    const int*   mask = (const int*)  d_in[3];
    const float* w_q  = (const float*)d_in[4];
    const float* b_q  = (const float*)d_in[5];
    const float* w_k  = (const float*)d_in[6];
    const float* b_k  = (const float*)d_in[7];
    const float* w_v  = (const float*)d_in[8];
    const float* b_v  = (const float*)d_in[9];
    const float* w_o  = (const float*)d_in[10];
    const float* b_o  = (const float*)d_in[11];

    char* ws = (char*)d_ws;
    bf16* Abf_q = (bf16*)(ws);
    bf16* Abf_k = (bf16*)(ws + 8388608);
    bf16* Abf_v = (bf16*)(ws + 16777216);
    bf16* ctx   = (bf16*)(ws);                // aliases Abf_q after proj consumes it
    bf16* Qh    = (bf16*)(ws + 25165824);
    bf16* Kh    = (bf16*)(ws + 33554432);
    bf16* Vt    = (bf16*)(ws + 41943040);
    bf16* Wbf_q = (bf16*)(ws + 50331648);
    bf16* Wbf_k = (bf16*)(ws + 52428800);
    bf16* Wbf_v = (bf16*)(ws + 54525952);
    bf16* Wbf_o = (bf16*)(ws + 56623104);
    int*  inv   = (int*) (ws + 58720256);
    int*  cntb  = (int*) (ws + 58736640);

    dim3 blk(256);
    prep<<<dim3(8194), blk, 0, stream>>>(q_in, k_in, v_in, w_q, w_k, w_v, w_o,
                                         mask, Abf_q, Abf_k, Abf_v,
                                         Wbf_q, Wbf_k, Wbf_v, Wbf_o, inv, cntb);

    gemm_proj<<<dim3(768), blk, 0, stream>>>(
        Abf_q, Abf_k, Abf_v, Wbf_q, Wbf_k, Wbf_v, b_q, b_k, b_v, inv, cntb,
        Qh, Kh, Vt);

    attn_mfma<<<dim3(Sn/128, Bn*Hn), dim3(512), 0, stream>>>(Qh, Kh, Vt, cntb, ctx);

    gemm_out<<<dim3(512), blk, 0, stream>>>(ctx, Wbf_o, b_o, (float*)d_out);
}